// Round 3
// baseline (276.019 us; speedup 1.0000x reference)
//
#include <hip/hip_runtime.h>
#include <stdint.h>

typedef uint32_t u32;
typedef uint64_t u64;

#define BN 16
#define CLS 80
#define ROWF 85
#define KSEL 512
#define NBKT 4096
#define CONF_T 0.001f
#define NMS_T 0.5f

__device__ __forceinline__ u32 flip_desc(float x) {
    u32 u = __float_as_uint(x);
    u32 m = (u & 0x80000000u) ? ~u : (u | 0x80000000u); // monotonic ascending
    return ~m;                                          // descending key
}
__device__ __forceinline__ float unflip(u32 key) {
    u32 m = ~key;
    u32 u = (m & 0x80000000u) ? (m & 0x7fffffffu) : ~m;
    return __uint_as_float(u);
}
__device__ __forceinline__ int conf_bucket(float cm) {
    float f = floorf(cm * 4096.0f);
    f = fminf(f, 4095.0f);
    f = fmaxf(f, 0.0f);
    return (int)f;
}

// ---------------- K1: per-row conf key + per-image value histogram ----------------
__global__ __launch_bounds__(128) void k1_keys(const float* __restrict__ pred,
                                               u32* __restrict__ keys,
                                               u32* __restrict__ hist,
                                               int totalRows, int N) {
    __shared__ float buf[128 * ROWF]; // 43,520 B
    int nrow = min(128, totalRows - blockIdx.x * 128);
    if (nrow <= 0) return;
    int nf4 = nrow * ROWF / 4;
    const float4* p4 = (const float4*)pred;
    float4* b4 = (float4*)buf;
    long long base4 = (long long)blockIdx.x * (128 * ROWF / 4);
    for (int k = threadIdx.x; k < nf4; k += 128) b4[k] = p4[base4 + k];
    __syncthreads();
    int r = threadIdx.x;
    if (r < nrow) {
        const float* p = &buf[r * ROWF];
        float obj = p[4];
        float mx = p[5];
        #pragma unroll
        for (int c = 1; c < CLS; c++) { float v = p[5 + c]; if (v > mx) mx = v; }
        float conf = obj * mx;
        float w = p[2], h = p[3];
        bool ok = (conf > CONF_T) && (w > 2.0f) && (w < 10000.0f) && (h > 2.0f) && (h < 10000.0f);
        bool fin = true;
        #pragma unroll
        for (int c = 0; c < ROWF; c++) {
            u32 bb = __float_as_uint(p[c]);
            if ((bb & 0x7f800000u) == 0x7f800000u) fin = false;
        }
        ok = ok && fin;
        float cm = ok ? conf : -1.0f;
        int row = blockIdx.x * 128 + r;
        keys[row] = flip_desc(cm);
        int b = row / N;
        atomicAdd(&hist[b * NBKT + conf_bucket(cm)], 1u);
    }
}

// ---------------- K2b: per-image threshold bucket from histogram ----------------
__global__ __launch_bounds__(256) void k2b_thresh(const u32* __restrict__ hist,
                                                  u32* __restrict__ tbinfo) {
    int b = blockIdx.x;
    const u32* H = hist + b * NBKT;
    __shared__ u32 part[256];
    __shared__ u32 pre[256];
    int t = threadIdx.x;
    u32 s = 0;
    #pragma unroll
    for (int k = 0; k < 16; k++) s += H[NBKT - 1 - (t * 16 + k)];
    part[t] = s;
    __syncthreads();
    if (t == 0) { u32 c = 0; for (int i = 0; i < 256; i++) { pre[i] = c; c += part[i]; } }
    __syncthreads();
    u32 cum = pre[t];
    if (cum < KSEL && cum + part[t] >= KSEL) { // unique crossing thread
        for (int k = 0; k < 16; k++) {
            int bidx = NBKT - 1 - (t * 16 + k);
            u32 h = H[bidx];
            if (cum + h >= KSEL) {
                tbinfo[b * 2 + 0] = (u32)bidx; // threshold bucket
                tbinfo[b * 2 + 1] = cum;       // nAbove (< 512)
                break;
            }
            cum += h;
        }
    }
}

// ---------------- K2c: parallel compaction into above/tie candidate lists ----------------
__global__ __launch_bounds__(256) void k2c_compact(const u32* __restrict__ keys,
                                                   const u32* __restrict__ tbinfo,
                                                   u32* __restrict__ cnt,
                                                   u64* __restrict__ above,
                                                   u64* __restrict__ ties, int N) {
    int b = blockIdx.x >> 3;   // 8 blocks per image
    int chunk = blockIdx.x & 7;
    u32 Tb = tbinfo[b * 2];
    const u32* kk = keys + (long long)b * N;
    u64* av = above + b * KSEL;
    u64* tv = ties + (long long)b * N;
    for (int i = chunk * 256 + threadIdx.x; i < N; i += 2048) {
        u32 e = kk[i];
        u32 bk = (u32)conf_bucket(unflip(e));
        if (bk > Tb) {
            u32 p = atomicAdd(&cnt[b * 2], 1u);
            av[p] = ((u64)e << 32) | (u32)i;
        } else if (bk == Tb) {
            u32 p = atomicAdd(&cnt[b * 2 + 1], 1u);
            tv[p] = ((u64)e << 32) | (u32)i;
        }
    }
}

// ---------------- K2d: exact select among ties + bitonic sort 512 ----------------
__global__ __launch_bounds__(256) void k2d_final(const u64* __restrict__ above,
                                                 const u64* __restrict__ ties,
                                                 const u32* __restrict__ tbinfo,
                                                 const u32* __restrict__ cnt,
                                                 u32* __restrict__ selidx, int N) {
    int b = blockIdx.x;
    __shared__ u64 skey[KSEL];
    __shared__ u32 hist[256];
    __shared__ u64 sh_prefix;
    __shared__ u32 sh_rem, sh_cnt2;
    int tid = threadIdx.x;
    u32 nA = tbinfo[b * 2 + 1];
    u32 ntie = cnt[b * 2 + 1];
    u32 t = KSEL - nA;
    const u64* av = above + b * KSEL;
    const u64* tv = ties + (long long)b * N;
    for (u32 i = tid; i < nA; i += 256) skey[i] = av[i];
    if (ntie == t) {
        for (u32 j = tid; j < t; j += 256) skey[nA + j] = tv[j];
    } else {
        // exact radix select: t-th smallest u64 (all values distinct: low 32 = unique idx)
        if (tid == 0) { sh_prefix = 0; sh_rem = t; }
        for (int byte = 7; byte >= 0; byte--) {
            __syncthreads();
            hist[tid] = 0;
            __syncthreads();
            u64 pfx = sh_prefix;
            for (u32 i = tid; i < ntie; i += 256) {
                u64 e = tv[i];
                if (byte == 7 || (e >> ((byte + 1) * 8)) == pfx)
                    atomicAdd(&hist[(u32)(e >> (byte * 8)) & 255u], 1u);
            }
            __syncthreads();
            if (tid == 0) {
                u32 rem = sh_rem, cum = 0; int c = 0;
                for (; c < 256; c++) { if (cum + hist[c] >= rem) break; cum += hist[c]; }
                sh_rem = rem - cum;
                sh_prefix = (pfx << 8) | (u32)c;
            }
        }
        __syncthreads();
        u64 Tu = sh_prefix;
        if (tid == 0) sh_cnt2 = 0;
        __syncthreads();
        for (u32 i = tid; i < ntie; i += 256) {
            u64 e = tv[i];
            if (e <= Tu) { u32 p = atomicAdd(&sh_cnt2, 1u); skey[nA + p] = e; }
        }
    }
    __syncthreads();
    // bitonic sort 512 ascending => conf desc, idx asc (== lax.top_k order)
    for (int k = 2; k <= KSEL; k <<= 1) {
        for (int j = k >> 1; j > 0; j >>= 1) {
            for (int i = tid; i < KSEL; i += 256) {
                int l = i ^ j;
                if (l > i) {
                    bool dir = ((i & k) == 0);
                    u64 a = skey[i], c = skey[l];
                    if ((a > c) == dir) { skey[i] = c; skey[l] = a; }
                }
            }
            __syncthreads();
        }
    }
    for (int i = tid; i < KSEL; i += 256) selidx[b * KSEL + i] = (u32)(skey[i] & 0xffffffffu);
}

// ---------------- K3: gather selected rows ----------------
__global__ void k3_gather(const float* __restrict__ pred, const u32* __restrict__ selidx,
                          float* __restrict__ sel, int N) {
    int g = blockIdx.x * blockDim.x + threadIdx.x;
    if (g >= BN * KSEL) return;
    int b = g / KSEL;
    int idx = (int)selidx[g];
    const float* row = pred + ((long long)b * N + idx) * ROWF;
    float obj = row[4];
    float mx = row[5]; int am = 0;
    for (int c = 1; c < CLS; c++) { float v = row[5 + c]; if (v > mx) { mx = v; am = c; } }
    float conf = obj * mx;
    float cx = row[0], cy = row[1], w = row[2], h = row[3];
    bool ok = (conf > CONF_T) && (w > 2.0f) && (w < 10000.0f) && (h > 2.0f) && (h < 10000.0f);
    bool fin = true;
    for (int c = 0; c < ROWF; c++) {
        u32 bb = __float_as_uint(row[c]);
        if ((bb & 0x7f800000u) == 0x7f800000u) fin = false;
    }
    ok = ok && fin;
    float off = (float)am * 10000.0f;
    float x1 = cx - w * 0.5f, y1 = cy - h * 0.5f;
    float x2 = cx + w * 0.5f, y2 = cy + h * 0.5f;
    float* s = sel + (long long)g * 8;
    s[0] = x1 + off; s[1] = y1; s[2] = x2 + off; s[3] = y2;
    s[4] = conf; s[5] = mx; s[6] = (float)am; s[7] = ok ? 1.0f : 0.0f;
}

// ---------------- K4: 512x512 iou>thres bitmatrix, TRANSPOSED [b][w][i] ----------------
__global__ __launch_bounds__(256) void k4_iou(const float* __restrict__ sel, u64* __restrict__ matT) {
    int b = blockIdx.x >> 4;
    int t = ((blockIdx.x & 15) << 8) + threadIdx.x;
    int w = t >> 9;
    int i = t & (KSEL - 1);
    __shared__ float BX[KSEL * 4]; // 8KB
    const float* S = sel + (long long)b * KSEL * 8;
    const float4* S4 = (const float4*)S;
    float4* B4 = (float4*)BX;
    for (int j = threadIdx.x; j < KSEL; j += 256) B4[j] = S4[j * 2];
    __syncthreads();
    float x1 = BX[i * 4 + 0], y1 = BX[i * 4 + 1], x2 = BX[i * 4 + 2], y2 = BX[i * 4 + 3];
    float a1 = __fmul_rn(__fsub_rn(x2, x1), __fsub_rn(y2, y1));
    u64 bits = 0;
    int j0 = w * 64;
    const float4* BB = (const float4*)BX;
    for (int jj = 0; jj < 64; jj++) {
        float4 bj = BB[j0 + jj]; // broadcast: whole wave shares w
        float ix = fmaxf(__fsub_rn(fminf(x2, bj.z), fmaxf(x1, bj.x)), 0.0f);
        float iy = fmaxf(__fsub_rn(fminf(y2, bj.w), fmaxf(y1, bj.y)), 0.0f);
        float inter = __fmul_rn(ix, iy);
        float a2 = __fmul_rn(__fsub_rn(bj.z, bj.x), __fsub_rn(bj.w, bj.y));
        float denom = __fadd_rn(__fsub_rn(__fadd_rn(a1, a2), inter), 1e-9f);
        float iou = __fdiv_rn(inter, denom);
        if (iou > NMS_T) bits |= (1ull << jj);
    }
    matT[((long long)b * 8 + w) * KSEL + i] = bits; // coalesced
}

// ---------------- K5: serial keep-scan (bitwise only) + parallel merge ----------------
__global__ __launch_bounds__(64) void k5_nms(const float* __restrict__ sel,
                                             const u64* __restrict__ matT,
                                             float* __restrict__ out) {
    int b = blockIdx.x;
    int lane = threadIdx.x;
    __shared__ float S[KSEL * 8];           // 16KB
    __shared__ u64 MT[8 * KSEL];            // 32KB, [w][i]
    __shared__ float MG[KSEL * 4];          // 8KB
    __shared__ unsigned short TGT[KSEL];    // 1KB
    const float4* gs = (const float4*)(sel + (long long)b * KSEL * 8);
    float4* s4 = (float4*)S;
    for (int i = lane; i < KSEL * 2; i += 64) s4[i] = gs[i];
    const ulonglong2* gm2 = (const ulonglong2*)(matT + (long long)b * 8 * KSEL);
    ulonglong2* m2 = (ulonglong2*)MT;
    for (int i = lane; i < 4 * KSEL; i += 64) m2[i] = gm2[i];
    __syncthreads();

    u64 aliveW[8], keepW[8], okW[8];
    #pragma unroll
    for (int w = 0; w < 8; w++) {
        bool okb = S[(w * 64 + lane) * 8 + 7] > 0.5f;
        okW[w] = __ballot(okb);
        aliveW[w] = okW[w];
        keepW[w] = 0;
    }

    // ---- phase 1: serial scan, pure bitmask algebra, 2-deep LDS prefetch ----
    u64 A[8], Bb[8];
    #pragma unroll
    for (int w = 0; w < 8; w++) { A[w] = MT[w * KSEL + 0]; Bb[w] = MT[w * KSEL + 1]; }
    #pragma unroll
    for (int wi = 0; wi < 8; wi++) {
        #pragma unroll 1
        for (int bi = 0; bi < 64; bi += 2) {
            int i = wi * 64 + bi;
            {
                u64 row[8];
                #pragma unroll
                for (int w = 0; w < 8; w++) row[w] = A[w];
                int ip = (i + 2 < KSEL) ? i + 2 : KSEL - 1;
                #pragma unroll
                for (int w = 0; w < 8; w++) A[w] = MT[w * KSEL + ip];
                if ((aliveW[wi] >> bi) & 1ull) {
                    keepW[wi] |= 1ull << bi;
                    #pragma unroll
                    for (int w = 0; w < 8; w++) aliveW[w] &= ~row[w];
                }
            }
            {
                u64 row[8];
                #pragma unroll
                for (int w = 0; w < 8; w++) row[w] = Bb[w];
                int ip = (i + 3 < KSEL) ? i + 3 : KSEL - 1;
                #pragma unroll
                for (int w = 0; w < 8; w++) Bb[w] = MT[w * KSEL + ip];
                if ((aliveW[wi] >> (bi + 1)) & 1ull) {
                    keepW[wi] |= 1ull << (bi + 1);
                    #pragma unroll
                    for (int w = 0; w < 8; w++) aliveW[w] &= ~row[w];
                }
            }
        }
    }

    // ---- phase 2a: per-column merge target = first kept bit of row j (M symmetric) ----
    #pragma unroll 1
    for (int r = 0; r < 8; r++) {
        int j = r * 64 + lane;
        int tgt = 0xffff;
        if ((okW[r] >> lane) & 1ull) {
            #pragma unroll
            for (int w = 7; w >= 0; w--) {
                u64 m = MT[w * KSEL + j] & keepW[w];
                if (m) tgt = w * 64 + (int)__builtin_ctzll(m);
            }
        }
        TGT[j] = (unsigned short)tgt;
    }
    __syncthreads();

    // ---- phase 2b: per kept k, deterministic ascending-j weighted merge ----
    #pragma unroll 1
    for (int r = 0; r < 8; r++) {
        int k = r * 64 + lane;
        if ((keepW[r] >> lane) & 1ull) {
            float s0 = 0.f, s1 = 0.f, s2 = 0.f, s3 = 0.f, sw = 0.f;
            #pragma unroll 1
            for (int w = 0; w < 8; w++) {
                u64 m = MT[w * KSEL + k] & okW[w];
                while (m) {
                    int j = w * 64 + (int)__builtin_ctzll(m);
                    m &= m - 1;
                    if (TGT[j] == (unsigned short)k) {
                        float c = S[j * 8 + 4];
                        s0 += c * S[j * 8 + 0]; s1 += c * S[j * 8 + 1];
                        s2 += c * S[j * 8 + 2]; s3 += c * S[j * 8 + 3];
                        sw += c;
                    }
                }
            }
            float d = sw + 1e-12f;
            MG[k * 4 + 0] = s0 / d; MG[k * 4 + 1] = s1 / d;
            MG[k * 4 + 2] = s2 / d; MG[k * 4 + 3] = s3 / d;
        }
    }
    __syncthreads();

    // ---- output: compact kept rows in order, zero tail ----
    int nk = 0;
    #pragma unroll
    for (int w = 0; w < 8; w++) nk += __popcll(keepW[w]);
    float* ob = out + (long long)b * KSEL * 7;
    for (int i = lane; i < KSEL; i += 64) {
        int wi = i >> 6, bi = i & 63;
        if ((keepW[wi] >> bi) & 1ull) {
            int rank = 0;
            for (int w = 0; w < wi; w++) rank += __popcll(keepW[w]);
            rank += __popcll(keepW[wi] & ((1ull << bi) - 1ull));
            float off = S[i * 8 + 6] * 10000.0f;
            float* o = ob + rank * 7;
            o[0] = MG[i * 4 + 0] - off; o[1] = MG[i * 4 + 1];
            o[2] = MG[i * 4 + 2] - off; o[3] = MG[i * 4 + 3];
            o[4] = S[i * 8 + 4]; o[5] = S[i * 8 + 5]; o[6] = S[i * 8 + 6];
        }
    }
    for (int p = nk + lane; p < KSEL; p += 64) {
        float* o = ob + p * 7;
        #pragma unroll
        for (int c = 0; c < 7; c++) o[c] = 0.0f;
    }
}

extern "C" void kernel_launch(void* const* d_in, const int* in_sizes, int n_in,
                              void* d_out, int out_size, void* d_ws, size_t ws_size,
                              hipStream_t stream) {
    const float* pred = (const float*)d_in[0];
    float* out = (float*)d_out;
    int total = in_sizes[0];
    int N = total / (BN * ROWF); // 22743
    int totalRows = BN * N;

    char* ws = (char*)d_ws;
    size_t o = 0;
    u32* hist = (u32*)(ws + o);    o += (size_t)BN * NBKT * 4;        // 262144
    u32* cnt = (u32*)(ws + o);     o += (size_t)BN * 2 * 4;           // 128
    u32* tbinfo = (u32*)(ws + o);  o += (size_t)BN * 2 * 4;           // 128
    u32* keys = (u32*)(ws + o);    o += (size_t)totalRows * 4;
    u64* above = (u64*)(ws + o);   o += (size_t)BN * KSEL * 8;
    u64* ties = (u64*)(ws + o);    o += (size_t)BN * N * 8;
    u32* selidx = (u32*)(ws + o);  o += (size_t)BN * KSEL * 4;
    float* sel = (float*)(ws + o); o += (size_t)BN * KSEL * 8 * 4;
    u64* matT = (u64*)(ws + o);    o += (size_t)BN * KSEL * 8 * 8;
    (void)ws_size;

    // zero hist + cnt (graph-capturable async memset)
    hipMemsetAsync(hist, 0, (size_t)BN * NBKT * 4 + (size_t)BN * 2 * 4, stream);

    k1_keys<<<(totalRows + 127) / 128, 128, 0, stream>>>(pred, keys, hist, totalRows, N);
    k2b_thresh<<<BN, 256, 0, stream>>>(hist, tbinfo);
    k2c_compact<<<BN * 8, 256, 0, stream>>>(keys, tbinfo, cnt, above, ties, N);
    k2d_final<<<BN, 256, 0, stream>>>(above, ties, tbinfo, cnt, selidx, N);
    k3_gather<<<(BN * KSEL + 255) / 256, 256, 0, stream>>>(pred, selidx, sel, N);
    k4_iou<<<BN * 16, 256, 0, stream>>>(sel, matT);
    k5_nms<<<BN, 64, 0, stream>>>(sel, matT, out);
}

// Round 4
// 187.665 us; speedup vs baseline: 1.4708x; 1.4708x over previous
//
#include <hip/hip_runtime.h>
#include <stdint.h>

typedef uint32_t u32;
typedef uint64_t u64;

#define BN 16
#define CLS 80
#define ROWF 85
#define KSEL 512
#define NBKT 4096
#define TCAP 2048
#define CONF_T 0.001f
#define NMS_T 0.5f

__device__ __forceinline__ u32 flip_desc(float x) {
    u32 u = __float_as_uint(x);
    u32 m = (u & 0x80000000u) ? ~u : (u | 0x80000000u); // monotonic ascending
    return ~m;                                          // descending key
}
__device__ __forceinline__ float unflip(u32 key) {
    u32 m = ~key;
    u32 u = (m & 0x80000000u) ? (m & 0x7fffffffu) : ~m;
    return __uint_as_float(u);
}
__device__ __forceinline__ int conf_bucket(float cm) {
    float f = floorf(cm * 4096.0f);
    f = fminf(f, 4095.0f);
    f = fmaxf(f, 0.0f);
    return (int)f;
}

// ---------------- K1: per-row conf key (lean: no atomics) ----------------
__global__ __launch_bounds__(256) void k1_keys(const float* __restrict__ pred,
                                               u32* __restrict__ keys, int totalRows) {
    __shared__ float buf[128 * ROWF]; // 43,520 B -> 3 blocks/CU, 12 waves/CU
    int row0 = blockIdx.x * 128;
    int nrow = min(128, totalRows - row0);
    if (nrow <= 0) return;
    int nf4 = nrow * ROWF / 4; // nrow % 4 == 0 always (128 or 112 tail)
    const float4* p4 = (const float4*)(pred + (long long)row0 * ROWF);
    float4* b4 = (float4*)buf;
    for (int k = threadIdx.x; k < nf4; k += 256) b4[k] = p4[k];
    __syncthreads();
    int r = threadIdx.x;
    if (r < nrow) {
        const float* p = &buf[r * ROWF];
        float obj = p[4];
        float mx = p[5];
        #pragma unroll
        for (int c = 1; c < CLS; c++) { float v = p[5 + c]; if (v > mx) mx = v; }
        float conf = obj * mx;
        float w = p[2], h = p[3];
        bool ok = (conf > CONF_T) && (w > 2.0f) && (w < 10000.0f) && (h > 2.0f) && (h < 10000.0f);
        bool fin = true;
        #pragma unroll
        for (int c = 0; c < ROWF; c++) {
            u32 bb = __float_as_uint(p[c]);
            if ((bb & 0x7f800000u) == 0x7f800000u) fin = false;
        }
        ok = ok && fin;
        float cm = ok ? conf : -1.0f;
        keys[row0 + r] = flip_desc(cm);
    }
}

// ---------------- K2_all: per-image hist + threshold + compact + select + sort + gather ----------------
__global__ __launch_bounds__(256) void k2_all(const float* __restrict__ pred,
                                              const u32* __restrict__ keys,
                                              float* __restrict__ sel, int N) {
    int b = blockIdx.x;
    const u32* kk = keys + (long long)b * N;
    __shared__ u32 hist[NBKT];   // 16KB
    __shared__ u64 above[KSEL];  // 4KB
    __shared__ u64 ties[TCAP];   // 16KB
    __shared__ u64 skey[KSEL];   // 4KB
    __shared__ u32 h256[256];    // 1KB
    __shared__ u32 pre[256];     // 1KB
    __shared__ u32 sh_Tb, sh_nA, sh_cA, sh_cT, sh_rem, sh_cnt2;
    __shared__ u64 sh_pfx;
    int tid = threadIdx.x;
    for (int i = tid; i < NBKT; i += 256) hist[i] = 0;
    if (tid == 0) { sh_cA = 0; sh_cT = 0; }
    __syncthreads();
    // pass 1: value-space histogram
    for (int i = tid; i < N; i += 256)
        atomicAdd(&hist[conf_bucket(unflip(kk[i]))], 1u);
    __syncthreads();
    // threshold scan from top
    {
        u32 s = 0;
        #pragma unroll
        for (int k = 0; k < 16; k++) s += hist[NBKT - 1 - (tid * 16 + k)];
        h256[tid] = s;
    }
    __syncthreads();
    if (tid == 0) { u32 c = 0; for (int i = 0; i < 256; i++) { pre[i] = c; c += h256[i]; } }
    __syncthreads();
    {
        u32 cum = pre[tid];
        if (cum < KSEL && cum + h256[tid] >= KSEL) {
            for (int k = 0; k < 16; k++) {
                int bidx = NBKT - 1 - (tid * 16 + k);
                u32 h = hist[bidx];
                if (cum + h >= KSEL) { sh_Tb = (u32)bidx; sh_nA = cum; break; }
                cum += h;
            }
        }
    }
    __syncthreads();
    u32 Tb = sh_Tb, nA = sh_nA;
    // pass 2: compact into above / ties
    for (int i = tid; i < N; i += 256) {
        u32 e = kk[i];
        u32 bk = (u32)conf_bucket(unflip(e));
        if (bk > Tb) { u32 p = atomicAdd(&sh_cA, 1u); above[p] = ((u64)e << 32) | (u32)i; }
        else if (bk == Tb) { u32 p = atomicAdd(&sh_cT, 1u); if (p < TCAP) ties[p] = ((u64)e << 32) | (u32)i; }
    }
    __syncthreads();
    u32 ntie = min(sh_cT, (u32)TCAP);
    u32 t = KSEL - nA;
    for (u32 i = tid; i < nA; i += 256) skey[i] = above[i];
    if (ntie == t) {
        for (u32 j = tid; j < t; j += 256) skey[nA + j] = ties[j];
    } else {
        // exact radix select: t-th smallest u64 among ties (all distinct: low32 unique idx)
        if (tid == 0) { sh_pfx = 0; sh_rem = t; }
        for (int byte = 7; byte >= 0; byte--) {
            __syncthreads();
            h256[tid] = 0;
            __syncthreads();
            u64 pfx = sh_pfx;
            for (u32 i = tid; i < ntie; i += 256) {
                u64 e = ties[i];
                if (byte == 7 || (e >> ((byte + 1) * 8)) == pfx)
                    atomicAdd(&h256[(u32)(e >> (byte * 8)) & 255u], 1u);
            }
            __syncthreads();
            if (tid == 0) {
                u32 rem = sh_rem, cum = 0; int c = 0;
                for (; c < 256; c++) { if (cum + h256[c] >= rem) break; cum += h256[c]; }
                sh_rem = rem - cum;
                sh_pfx = (pfx << 8) | (u32)c;
            }
        }
        __syncthreads();
        u64 Tu = sh_pfx;
        if (tid == 0) sh_cnt2 = 0;
        __syncthreads();
        for (u32 i = tid; i < ntie; i += 256) {
            u64 e = ties[i];
            if (e <= Tu) { u32 p = atomicAdd(&sh_cnt2, 1u); skey[nA + p] = e; }
        }
    }
    __syncthreads();
    // bitonic sort 512 ascending => conf desc, idx asc (== lax.top_k order)
    for (int k = 2; k <= KSEL; k <<= 1) {
        for (int j = k >> 1; j > 0; j >>= 1) {
            for (int i = tid; i < KSEL; i += 256) {
                int l = i ^ j;
                if (l > i) {
                    bool dir = ((i & k) == 0);
                    u64 a = skey[i], c = skey[l];
                    if ((a > c) == dir) { skey[i] = c; skey[l] = a; }
                }
            }
            __syncthreads();
        }
    }
    // gather selected rows -> sel
    for (int g = tid; g < KSEL; g += 256) {
        int idx = (int)(skey[g] & 0xffffffffu);
        const float* row = pred + ((long long)b * N + idx) * ROWF;
        float obj = row[4];
        float mx = row[5]; int am = 0;
        for (int c = 1; c < CLS; c++) { float v = row[5 + c]; if (v > mx) { mx = v; am = c; } }
        float conf = obj * mx;
        float cx = row[0], cy = row[1], w = row[2], h = row[3];
        bool ok = (conf > CONF_T) && (w > 2.0f) && (w < 10000.0f) && (h > 2.0f) && (h < 10000.0f);
        bool fin = true;
        for (int c = 0; c < ROWF; c++) {
            u32 bb = __float_as_uint(row[c]);
            if ((bb & 0x7f800000u) == 0x7f800000u) fin = false;
        }
        ok = ok && fin;
        float off = (float)am * 10000.0f;
        float x1 = cx - w * 0.5f, y1 = cy - h * 0.5f;
        float x2 = cx + w * 0.5f, y2 = cy + h * 0.5f;
        float* s = sel + ((long long)b * KSEL + g) * 8;
        s[0] = x1 + off; s[1] = y1; s[2] = x2 + off; s[3] = y2;
        s[4] = conf; s[5] = mx; s[6] = (float)am; s[7] = ok ? 1.0f : 0.0f;
    }
}

// ---------------- K4: 512x512 iou>thres bitmatrix, TRANSPOSED [b][w][i] ----------------
__global__ __launch_bounds__(256) void k4_iou(const float* __restrict__ sel, u64* __restrict__ matT) {
    int b = blockIdx.x >> 4;
    int t = ((blockIdx.x & 15) << 8) + threadIdx.x;
    int w = t >> 9;
    int i = t & (KSEL - 1);
    __shared__ float BX[KSEL * 4]; // 8KB
    const float4* S4 = (const float4*)(sel + (long long)b * KSEL * 8);
    float4* B4 = (float4*)BX;
    for (int j = threadIdx.x; j < KSEL; j += 256) B4[j] = S4[j * 2];
    __syncthreads();
    float x1 = BX[i * 4 + 0], y1 = BX[i * 4 + 1], x2 = BX[i * 4 + 2], y2 = BX[i * 4 + 3];
    float a1 = __fmul_rn(__fsub_rn(x2, x1), __fsub_rn(y2, y1));
    u64 bits = 0;
    int j0 = w * 64;
    const float4* BB = (const float4*)BX;
    for (int jj = 0; jj < 64; jj++) {
        float4 bj = BB[j0 + jj]; // broadcast: whole wave shares w
        float ix = fmaxf(__fsub_rn(fminf(x2, bj.z), fmaxf(x1, bj.x)), 0.0f);
        float iy = fmaxf(__fsub_rn(fminf(y2, bj.w), fmaxf(y1, bj.y)), 0.0f);
        float inter = __fmul_rn(ix, iy);
        float a2 = __fmul_rn(__fsub_rn(bj.z, bj.x), __fsub_rn(bj.w, bj.y));
        float denom = __fadd_rn(__fsub_rn(__fadd_rn(a1, a2), inter), 1e-9f);
        float iou = __fdiv_rn(inter, denom);
        if (iou > NMS_T) bits |= (1ull << jj);
    }
    matT[((long long)b * 8 + w) * KSEL + i] = bits; // coalesced
}

// ---------------- K5: chunked scalar keep-scan + parallel merge ----------------
__global__ __launch_bounds__(256) void k5_nms(const float* __restrict__ sel,
                                              const u64* __restrict__ matT,
                                              float* __restrict__ out) {
    int b = blockIdx.x;
    int tid = threadIdx.x;
    int lane = tid & 63;
    int wv = tid >> 6;
    __shared__ float S[KSEL * 8];        // 16KB
    __shared__ u64 MT[8 * KSEL];         // 32KB, [w][i]
    __shared__ float MG[KSEL * 4];       // 8KB
    __shared__ unsigned short TGT[KSEL]; // 1KB
    __shared__ u64 sh_keep[8], sh_ok[8];
    const float4* gs = (const float4*)(sel + (long long)b * KSEL * 8);
    float4* s4 = (float4*)S;
    for (int i = tid; i < KSEL * 2; i += 256) s4[i] = gs[i];
    const ulonglong2* gm2 = (const ulonglong2*)(matT + (long long)b * 8 * KSEL);
    ulonglong2* m2 = (ulonglong2*)MT;
    for (int i = tid; i < 4 * KSEL; i += 256) m2[i] = gm2[i];
    __syncthreads();

    if (wv == 0) {
        // a_bits: bit w = column (w*64+lane) still alive
        u32 a_bits = 0;
        #pragma unroll
        for (int w = 0; w < 8; w++)
            if (S[(w * 64 + lane) * 8 + 7] > 0.5f) a_bits |= 1u << w;
        #pragma unroll
        for (int w = 0; w < 8; w++) {
            u64 ow = __ballot((a_bits >> w) & 1u);
            if (lane == 0) sh_ok[w] = ow;
        }
        #pragma unroll 1
        for (int c = 0; c < 8; c++) {
            u64 cross[8];
            #pragma unroll
            for (int w = 0; w < 8; w++) cross[w] = MT[c * KSEL + w * 64 + lane];
            u64 intra = MT[c * KSEL + c * 64 + lane]; // == cross[c], reloaded for static indexing
            u64 aliveC = __ballot((a_bits >> c) & 1u);
            u32 ilo = (u32)intra, ihi = (u32)(intra >> 32);
            u64 keptC = 0;
            // serial 64-step resolution: symmetric matrix -> row m == lane m's column word
            #pragma unroll
            for (int m = 0; m < 64; m++) {
                u32 rl = __builtin_amdgcn_readlane(ilo, m);
                u32 rh = __builtin_amdgcn_readlane(ihi, m);
                u64 rowm = ((u64)rh << 32) | rl;
                u64 take = (aliveC >> m) & 1ull;
                u64 msk = (u64)0 - take;
                keptC |= take << m;
                aliveC &= ~(rowm & msk);
            }
            if (lane == 0) sh_keep[c] = keptC;
            // cross-chunk suppression: O(1) per lane, no reduction
            #pragma unroll
            for (int w = 0; w < 8; w++)
                if (cross[w] & keptC) a_bits &= ~(1u << w);
        }
    }
    __syncthreads();
    u64 keepW[8], okW[8];
    #pragma unroll
    for (int w = 0; w < 8; w++) { keepW[w] = sh_keep[w]; okW[w] = sh_ok[w]; }

    // phase 2a: per-column merge target = first kept bit of row j (M symmetric)
    for (int j = tid; j < KSEL; j += 256) {
        int r = j >> 6, ln = j & 63;
        int tgt = 0xffff;
        if ((okW[r] >> ln) & 1ull) {
            #pragma unroll
            for (int w = 7; w >= 0; w--) {
                u64 m = MT[w * KSEL + j] & keepW[w];
                if (m) tgt = w * 64 + (int)__builtin_ctzll(m);
            }
        }
        TGT[j] = (unsigned short)tgt;
    }
    __syncthreads();

    // phase 2b: per kept k, deterministic ascending-j weighted merge
    for (int k = tid; k < KSEL; k += 256) {
        int r = k >> 6, ln = k & 63;
        if ((keepW[r] >> ln) & 1ull) {
            float s0 = 0.f, s1 = 0.f, s2 = 0.f, s3 = 0.f, sw = 0.f;
            #pragma unroll 1
            for (int w = 0; w < 8; w++) {
                u64 m = MT[w * KSEL + k] & okW[w];
                while (m) {
                    int j = w * 64 + (int)__builtin_ctzll(m);
                    m &= m - 1;
                    if (TGT[j] == (unsigned short)k) {
                        float c = S[j * 8 + 4];
                        s0 += c * S[j * 8 + 0]; s1 += c * S[j * 8 + 1];
                        s2 += c * S[j * 8 + 2]; s3 += c * S[j * 8 + 3];
                        sw += c;
                    }
                }
            }
            float d = sw + 1e-12f;
            MG[k * 4 + 0] = s0 / d; MG[k * 4 + 1] = s1 / d;
            MG[k * 4 + 2] = s2 / d; MG[k * 4 + 3] = s3 / d;
        }
    }
    __syncthreads();

    // output: compact kept rows in order, zero tail
    int nk = 0;
    #pragma unroll
    for (int w = 0; w < 8; w++) nk += __popcll(keepW[w]);
    float* ob = out + (long long)b * KSEL * 7;
    for (int i = tid; i < KSEL; i += 256) {
        int wi = i >> 6, bi = i & 63;
        if ((keepW[wi] >> bi) & 1ull) {
            int rank = 0;
            for (int w = 0; w < wi; w++) rank += __popcll(keepW[w]);
            rank += __popcll(keepW[wi] & ((1ull << bi) - 1ull));
            float off = S[i * 8 + 6] * 10000.0f;
            float* o = ob + rank * 7;
            o[0] = MG[i * 4 + 0] - off; o[1] = MG[i * 4 + 1];
            o[2] = MG[i * 4 + 2] - off; o[3] = MG[i * 4 + 3];
            o[4] = S[i * 8 + 4]; o[5] = S[i * 8 + 5]; o[6] = S[i * 8 + 6];
        }
    }
    for (int p = nk + tid; p < KSEL; p += 256) {
        float* o = ob + p * 7;
        #pragma unroll
        for (int c = 0; c < 7; c++) o[c] = 0.0f;
    }
}

extern "C" void kernel_launch(void* const* d_in, const int* in_sizes, int n_in,
                              void* d_out, int out_size, void* d_ws, size_t ws_size,
                              hipStream_t stream) {
    const float* pred = (const float*)d_in[0];
    float* out = (float*)d_out;
    int total = in_sizes[0];
    int N = total / (BN * ROWF); // 22743
    int totalRows = BN * N;

    char* ws = (char*)d_ws;
    size_t o = 0;
    u32* keys = (u32*)(ws + o);    o += (size_t)totalRows * 4;
    float* sel = (float*)(ws + o); o += (size_t)BN * KSEL * 8 * 4;
    u64* matT = (u64*)(ws + o);    o += (size_t)BN * KSEL * 8 * 8;
    (void)ws_size;

    k1_keys<<<(totalRows + 127) / 128, 256, 0, stream>>>(pred, keys, totalRows);
    k2_all<<<BN, 256, 0, stream>>>(pred, keys, sel, N);
    k4_iou<<<BN * 16, 256, 0, stream>>>(sel, matT);
    k5_nms<<<BN, 256, 0, stream>>>(sel, matT, out);
}